// Round 14
// baseline (266.207 us; speedup 1.0000x reference)
//
#include <hip/hip_runtime.h>

#define N_PTS   20000
#define M_ATOMS 10000
#define DAT     64
#define HID     129
#define KNN     16
#define NLAYERS 3

#define A_HSTRIDE  132        // A row stride in HALVES (264 B, 8B-aligned)

#define GRIDL   24
#define NCELL   (GRIDL*GRIDL*GRIDL)   // 13824
#define CELL_H  4.0f
#define INV_H   0.25f
#define GORIG   (-48.0f)

#define KNN_NBLK   (N_PTS / 4)                    // 5000
#define A_GROUPS   (M_ATOMS / 8)                  // 1250 (8 atoms/wave)
#define PRE_NBLK   ((NLAYERS * A_GROUPS + 3) / 4) // 938

typedef _Float16 half2_t __attribute__((ext_vector_type(2)));

__device__ __forceinline__ float readlane_f(float v, int l) {
    return __int_as_float(__builtin_amdgcn_readlane(__float_as_int(v), l));
}
__device__ __forceinline__ int cell_of(float v) {
    int c = (int)floorf((v - GORIG) * INV_H);
    return c < 0 ? 0 : (c > GRIDL - 1 ? GRIDL - 1 : c);
}

// ================= grid build (h=4) =================
__global__ void grid_zero(int* __restrict__ counts) {
    int i = blockIdx.x * 256 + threadIdx.x;
    if (i <= NCELL) counts[i] = 0;
}

__global__ void grid_count(const float* __restrict__ y, int* __restrict__ counts,
                           int* __restrict__ acell) {
    int i = blockIdx.x * 256 + threadIdx.x;
    if (i >= M_ATOMS) return;
    float a = y[3*i], b = y[3*i+1], c = y[3*i+2];
    int cid = (cell_of(c) * GRIDL + cell_of(b)) * GRIDL + cell_of(a);
    acell[i] = cid;
    atomicAdd(&counts[cid], 1);
}

__global__ __launch_bounds__(1024) void grid_scan(const int* __restrict__ counts,
        int* __restrict__ starts, int* __restrict__ cursor) {
    __shared__ int part[1024];
    const int t = threadIdx.x;
    const int base = t * 14;                       // 1024*14 = 14336 >= 13824
    int loc[14]; int sum = 0;
#pragma unroll
    for (int i = 0; i < 14; ++i) {
        int idx = base + i;
        int c = (idx < NCELL) ? counts[idx] : 0;
        loc[i] = sum; sum += c;
    }
    part[t] = sum;
    for (int o = 1; o < 1024; o <<= 1) {
        __syncthreads();
        int v = (t >= o) ? part[t - o] : 0;
        __syncthreads();
        part[t] += v;
    }
    __syncthreads();
    int prev = (t > 0) ? part[t - 1] : 0;
#pragma unroll
    for (int i = 0; i < 14; ++i) {
        int idx = base + i;
        if (idx < NCELL) { int s = prev + loc[i]; starts[idx] = s; cursor[idx] = s; }
    }
    if (t == 1023) starts[NCELL] = part[1023];
}

__global__ void grid_scatter(const float* __restrict__ y, const int* __restrict__ acell,
                             int* __restrict__ cursor, float4* __restrict__ ypc,
                             int* __restrict__ aidx) {
    int i = blockIdx.x * 256 + threadIdx.x;
    if (i >= M_ATOMS) return;
    int cid = acell[i];
    int pos = atomicAdd(&cursor[cid], 1);
    float a = y[3*i], b = y[3*i+1], c = y[3*i+2];
    ypc[pos]  = make_float4(a, b, c, (a*a + b*b) + c*c);   // (y**2).sum(1) order
    aidx[pos] = i;
}

// ================= top-k primitive =================
__device__ __forceinline__ void topk_process(float d2, int ai, int lane,
        float& Ld, int& Li, float& kth, int& kidx, bool& filled) {
    const float INF = __builtin_inff();
    if (!filled) {                                  // bitonic-sort fill (wave-uniform)
        float v = d2; int ix = ai;
#pragma unroll
        for (int k = 2; k <= 64; k <<= 1)
#pragma unroll
            for (int j = k >> 1; j > 0; j >>= 1) {
                float ov = __shfl_xor(v, j);
                int   oi = __shfl_xor(ix, j);
                bool keepmin = (((lane & k) == 0) == ((lane & j) == 0));
                bool oless   = (ov < v) || (ov == v && oi < ix);
                bool take    = (keepmin == oless);
                v  = take ? ov : v;
                ix = take ? oi : ix;
            }
        Ld = (lane < KNN) ? v : INF;
        Li = (lane < KNN) ? ix : 0x7fffffff;
        kth  = readlane_f(v, 15);
        kidx = __builtin_amdgcn_readlane(ix, 15);
        filled = true;
        return;
    }
    bool adm = (d2 < kth) || (d2 == kth && ai < kidx);
    unsigned long long cand = __ballot(adm);
    if (cand) {
        do {
            int src = __builtin_ctzll(cand);
            cand &= cand - 1;
            float v  = readlane_f(d2, src);
            int   mi = __builtin_amdgcn_readlane(ai, src);
            bool pred = (Ld > v) || (Ld == v && Li > mi);   // lexicographic
            unsigned long long bal = __ballot(pred);
            int ins = __builtin_ctzll(bal);
            float pd = __shfl_up(Ld, 1);
            int   pi = __shfl_up(Li, 1);
            bool atins = (lane == ins);
            float tv = atins ? v  : pd;
            int   ti = atins ? mi : pi;
            Ld = pred ? tv : Ld;
            Li = pred ? ti : Li;
        } while (cand);
        kth  = readlane_f(Ld, 15);
        kidx = __builtin_amdgcn_readlane(Li, 15);
    }
}

// ================= fat kernel: knn query (blocks 0..4999) + A precompute =================
__global__ __launch_bounds__(256) void knn_pre(
        const float* __restrict__ x, const float* __restrict__ y,
        const int* __restrict__ starts, const float4* __restrict__ ypc,
        const int* __restrict__ aidx,
        int* __restrict__ oidx, float* __restrict__ odist,
        const float* __restrict__ feats, const float* __restrict__ W1,
        const float* __restrict__ b1, _Float16* __restrict__ A) {
    __shared__ int s_start[4][64];
    __shared__ int s_off[4][64];
    const int lane = threadIdx.x & 63;
    const int wid  = threadIdx.x >> 6;

    if (blockIdx.x >= KNN_NBLK) {
        // ---------- per-atom precompute: A[l][i] = feats[i] @ W1[l][64:128] + b1[l] (fp16) ----------
        int id = (blockIdx.x - KNN_NBLK) * 4 + wid;
        if (id >= NLAYERS * A_GROUPS) return;
        int l = id / A_GROUPS, g = id - l * A_GROUPS;
        int base_atom = g * 8;

        float f[8];
#pragma unroll
        for (int a = 0; a < 8; ++a) f[a] = feats[(base_atom + a) * DAT + lane];
        float a0[8], a1[8], a2[8];
#pragma unroll
        for (int a = 0; a < 8; ++a) { a0[a] = 0.f; a1[a] = 0.f; a2[a] = 0.f; }

        const float* Wl = W1 + (size_t)l * HID * HID;
#pragma unroll 4
        for (int d = 0; d < DAT; ++d) {
            const float* row = Wl + (64 + d) * HID;
            float w0 = row[2 * lane];
            float w1 = row[2 * lane + 1];
            float w2 = row[128];
#pragma unroll
            for (int a = 0; a < 8; ++a) {
                float s = readlane_f(f[a], d);
                a0[a] += s * w0;
                a1[a] += s * w1;
                a2[a] += s * w2;
            }
        }
        const float* b1l = b1 + l * HID;
        float bb0 = b1l[2 * lane], bb1 = b1l[2 * lane + 1], bb2 = b1l[128];
#pragma unroll
        for (int a = 0; a < 8; ++a) {
            _Float16* Ar = A + ((size_t)l * M_ATOMS + base_atom + a) * A_HSTRIDE;
            half2_t hv; hv.x = (_Float16)(a0[a] + bb0); hv.y = (_Float16)(a1[a] + bb1);
            ((half2_t*)Ar)[lane] = hv;
            if (lane == 0) Ar[128] = (_Float16)(a2[a] + bb2);
        }
        return;
    }

    // ---------- kNN query ----------
    const int n = blockIdx.x * 4 + wid;             // < 20000
    const float INF = __builtin_inff();

    const float qx = x[3*n], qy = x[3*n+1], qz = x[3*n+2];
    const float qs = (qx*qx + qy*qy) + qz*qz;       // (x**2).sum(1) order
    const int cx = cell_of(qx), cy = cell_of(qy), cz = cell_of(qz);

    float Ld = INF; int Li = 0x7fffffff;
    float kth = INF; int kidx = 0x7fffffff;
    bool filled = false;

    // rings 0..1: 9 contiguous x-runs, serial, center row first
    {
        int sS = 0, cnt = 0;
        if (lane < 9) {
            int dyv = lane % 3 - 1, dzv = lane / 3 - 1;
            int ny = cy + dyv, nz = cz + dzv;
            if (ny >= 0 && ny < GRIDL && nz >= 0 && nz < GRIDL) {
                int xl = max(cx - 1, 0), xh = min(cx + 1, GRIDL - 1);
                int cid0 = (nz * GRIDL + ny) * GRIDL + xl;
                sS  = starts[cid0];
                cnt = starts[cid0 + (xh - xl) + 1] - sS;
            }
        }
#pragma unroll
        for (int si = 0; si < 9; ++si) {
            const int s = (si == 0) ? 4 : (si <= 4 ? si - 1 : si);  // {4,0,1,2,3,5,6,7,8}
            const int ss = __builtin_amdgcn_readlane(sS, s);
            const int cc = __builtin_amdgcn_readlane(cnt, s);
            for (int b = 0; b < cc; b += 64) {
                int pos = b + lane; bool val = pos < cc;
                int a = val ? (ss + pos) : ss;
                float4 av = ypc[a];
                int    ai = aidx[a];
                float dot = (qx * av.x + qy * av.y) + qz * av.z;
                float d2  = (qs - 2.f * dot) + av.w;   // same algebra as reference
                if (!val) { d2 = INF; ai = 0x7fffffff; }
                topk_process(d2, ai, lane, Ld, Li, kth, kidx, filled);
            }
        }
    }

    // shells r>=2 (rare): lane-parallel segments + binary search
    int R = 1;
    while (R < GRIDL) {
        float bnd = (float)R * CELL_H - 0.125f;     // margin covers d2 rounding
        if (bnd * bnd > kth) break;                 // wave-uniform
        const int r  = R + 1;
        const int n1 = 2 * r + 1, m = 2 * r - 1;
        const int C1 = 2 * n1, C2 = 2 * m;
        const int S  = C1 + C2 + 2 * m * m;
        for (int base = 0; base < S; base += 64) {
            int sid = base + lane;
            int sS = 0, cnt = 0;
            if (sid < S) {
                int dy, dz, xlo, xhi;
                if (sid < C1) {
                    dz = (sid < n1) ? -r : r;
                    dy = (sid - ((sid < n1) ? 0 : n1)) - r;
                    xlo = cx - r; xhi = cx + r;
                } else if (sid < C1 + C2) {
                    int i = sid - C1;
                    dy = (i < m) ? -r : r;
                    dz = (i - ((i < m) ? 0 : m)) - (r - 1);
                    xlo = cx - r; xhi = cx + r;
                } else {
                    int i = sid - C1 - C2;
                    int pair = i >> 1, side = i & 1;
                    dz = (pair / m) - (r - 1);
                    dy = (pair % m) - (r - 1);
                    int xx = side ? cx + r : cx - r;
                    xlo = xx; xhi = xx;
                }
                int ny = cy + dy, nz = cz + dz;
                if (ny >= 0 && ny < GRIDL && nz >= 0 && nz < GRIDL) {
                    int xl = max(xlo, 0), xh = min(xhi, GRIDL - 1);
                    if (xl <= xh) {
                        int cid0 = (nz * GRIDL + ny) * GRIDL + xl;
                        sS  = starts[cid0];
                        cnt = starts[cid0 + (xh - xl) + 1] - sS;
                    }
                }
            }
            int incl = cnt;
#pragma unroll
            for (int o = 1; o < 64; o <<= 1) {
                int v = __shfl_up(incl, o);
                if (lane >= o) incl += v;
            }
            const int T = __builtin_amdgcn_readlane(incl, 63);
            if (T == 0) continue;
            s_start[wid][lane] = sS;
            s_off[wid][lane]   = incl - cnt;
            for (int b = 0; b < T; b += 64) {
                int pos = b + lane; bool val = pos < T;
                int c = 0;
                c += (s_off[wid][c + 32] <= pos) ? 32 : 0;
                c += (s_off[wid][c + 16] <= pos) ? 16 : 0;
                c += (s_off[wid][c + 8]  <= pos) ? 8  : 0;
                c += (s_off[wid][c + 4]  <= pos) ? 4  : 0;
                c += (s_off[wid][c + 2]  <= pos) ? 2  : 0;
                c += (s_off[wid][c + 1]  <= pos) ? 1  : 0;
                int a = s_start[wid][c] + (pos - s_off[wid][c]);
                a = val ? a : 0;
                float4 av = ypc[a];
                int    ai = aidx[a];
                float dot = (qx * av.x + qy * av.y) + qz * av.z;
                float d2  = (qs - 2.f * dot) + av.w;
                if (!val) { d2 = INF; ai = 0x7fffffff; }
                topk_process(d2, ai, lane, Ld, Li, kth, kidx, filled);
            }
        }
        R = r;
    }

    if (lane < KNN) {
        int ii = Li;
        float ax = y[3*ii], ay = y[3*ii+1], az = y[3*ii+2];
        float ddx = qx - ax, ddy = qy - ay, ddz = qz - az;
        float dist = (ddx*ddx + ddy*ddy) + ddz*ddz;   // ((x-y)**2).sum(-1) order
        oidx [n * KNN + lane] = ii;
        odist[n * KNN + lane] = dist;
    }
}

// ================= fused 3-layer MLP + groupnorm =================
// Round-10 f32-weights structure (naturally 64 VGPR) at 1024-thread blocks,
// PLAIN launch bound (no min-waves clause — forced bounds spilled in r11/r13).
// If VGPR stays 64: LDS 2 blocks/CU x 16 waves = 32 waves/CU occupancy cap.
__global__ __launch_bounds__(1024) void mlp_fused(
        const float* __restrict__ W1, const float* __restrict__ W2,
        const float* __restrict__ b2, const float* __restrict__ gnw,
        const float* __restrict__ gnb, const _Float16* __restrict__ A,
        const int* __restrict__ oidx, const float* __restrict__ odist,
        float* __restrict__ out) {
    __shared__ float2 w1s[64 * 64];   // 32KB [d][lane] = (W1[d][2l], W1[d][2l+1])
    __shared__ float2 w2s[64 * 64];   // 32KB [j][lane] = (W2[2j][l], W2[2j+1][l])
    const int wave = threadIdx.x >> 6, lane = threadIdx.x & 63;
    const int n0 = (blockIdx.x * 16 + wave) * 2;    // 625*16*2 == 20000

    int ikl0 = 0, ikl1 = 0; float dkl0 = 0.f, dkl1 = 0.f;
    if (lane < KNN) {
        ikl0 = oidx[n0 * KNN + lane];       dkl0 = odist[n0 * KNN + lane];
        ikl1 = oidx[(n0 + 1) * KNN + lane]; dkl1 = odist[(n0 + 1) * KNN + lane];
    }
    const int ho0 = ikl0 * A_HSTRIDE;               // half-offsets (valid lanes<16)
    const int ho1 = ikl1 * A_HSTRIDE;
    float pe0 = 1.f, pe1 = 1.f;

    for (int l = 0; l < NLAYERS; ++l) {
        if (l) __syncthreads();                     // prev layer done reading LDS
        const float* Wl  = W1 + (size_t)l * HID * HID;
        const float* W2l = W2 + (size_t)l * HID * DAT;
        for (int d = wave; d < 64; d += 16) {
            w1s[d * 64 + lane] = make_float2(Wl[d * HID + 2 * lane], Wl[d * HID + 2 * lane + 1]);
            w2s[d * 64 + lane] = make_float2(W2l[(2 * d) * DAT + lane], W2l[(2 * d + 1) * DAT + lane]);
        }
        const float wl0 = Wl[128 * HID + 2 * lane], wl1 = Wl[128 * HID + 2 * lane + 1];
        const float wl2 = Wl[128 * HID + 128];
        const float w1c = Wl[lane * HID + 128];
        const float w2c = W2l[128 * DAT + lane];
        const float b2v = 16.f * b2[l * DAT + lane];
        const float gw  = gnw[l * DAT + lane], gb = gnb[l * DAT + lane];

        // A-gathers issued before the staging barrier (latency hidden under it)
        const _Float16* Al = A + (size_t)l * M_ATOMS * A_HSTRIDE;
        half2_t Av0[KNN], Av1[KNN];
#pragma unroll
        for (int k = 0; k < KNN; ++k) {
            Av0[k] = ((const half2_t*)(Al + __builtin_amdgcn_readlane(ho0, k)))[lane];
            Av1[k] = ((const half2_t*)(Al + __builtin_amdgcn_readlane(ho1, k)))[lane];
        }
        float A2l0 = 0.f, A2l1 = 0.f;               // lane k: channel-128 of neighbor k
        if (lane < KNN) {
            A2l0 = (float)Al[ho0 + 128];
            A2l1 = (float)Al[ho1 + 128];
        }
        __syncthreads();                            // weights staged

        // layer 0: pe == 1 -> p-vector identical for all points
        float fpa = 0.f, fpb = 0.f, fpc = 0.f;
        if (l == 0) {
#pragma unroll 8
            for (int d = 0; d < 64; ++d) {
                float2 w = w1s[d * 64 + lane];
                fpa += w.x; fpb += w.y;
            }
            float v = w1c;
            v += __shfl_xor(v, 1);  v += __shfl_xor(v, 2);  v += __shfl_xor(v, 4);
            v += __shfl_xor(v, 8);  v += __shfl_xor(v, 16); v += __shfl_xor(v, 32);
            fpc = v;
        }

        auto point = [&](float& pe, const half2_t* Av, float A2l, float dkl) {
            float p0, p1, p2;
            if (l == 0) { p0 = fpa; p1 = fpb; p2 = fpc; }
            else {
                p0 = 0.f; p1 = 0.f;
#pragma unroll 8
                for (int d = 0; d < 64; ++d) {
                    float s = readlane_f(pe, d);
                    float2 w = w1s[d * 64 + lane];
                    p0 += w.x * s;
                    p1 += w.y * s;
                }
                float v = pe * w1c;                // dot(pe, W1[:,128]) via reduce
                v += __shfl_xor(v, 1);  v += __shfl_xor(v, 2);  v += __shfl_xor(v, 4);
                v += __shfl_xor(v, 8);  v += __shfl_xor(v, 16); v += __shfl_xor(v, 32);
                p2 = v;
            }

            // hs2 (scalar channel 128): lane k<16 computes its OWN term
            // (A2l, dkl lane-local; p2, wl2 wave-uniform), butterfly-sum.
            float t2 = 0.f;
            if (lane < KNN) {
                float u = p2 + A2l + dkl * wl2;
                t2 = fmaxf(u, 0.2f * u);           // == leaky (exact)
            }
            t2 += __shfl_xor(t2, 1);  t2 += __shfl_xor(t2, 2);  t2 += __shfl_xor(t2, 4);
            t2 += __shfl_xor(t2, 8);  t2 += __shfl_xor(t2, 16); t2 += __shfl_xor(t2, 32);
            const float hs2 = t2;

            // hsum channels (2l, 2l+1) = sum_k leaky(p + A[idx_k] + dist_k * wl)
            float hs0 = 0.f, hs1 = 0.f;
#pragma unroll
            for (int k = 0; k < KNN; ++k) {
                float ddk = readlane_f(dkl, k);
                float h0 = p0 + (float)Av[k].x + ddk * wl0; hs0 += fmaxf(h0, 0.2f * h0);
                float h1 = p1 + (float)Av[k].y + ddk * wl1; hs1 += fmaxf(h1, 0.2f * h1);
            }

            // msg = hsum @ W2 + K*b2
            float m0 = 0.f, m1 = 0.f;
#pragma unroll 8
            for (int j = 0; j < 64; j += 2) {
                float a0 = readlane_f(hs0, j),     a1 = readlane_f(hs1, j);
                float b0 = readlane_f(hs0, j + 1), b1 = readlane_f(hs1, j + 1);
                float2 wa = w2s[j * 64 + lane];
                float2 wb = w2s[(j + 1) * 64 + lane];
                m0 += wa.x * a0; m0 += wa.y * a1;
                m1 += wb.x * b0; m1 += wb.y * b1;
            }
            float m = (m0 + m1) + hs2 * w2c + b2v;

            // GroupNorm(2 groups of 32 channels) within aligned 32-lane halves
            float s1 = m;
            s1 += __shfl_xor(s1, 1);  s1 += __shfl_xor(s1, 2);  s1 += __shfl_xor(s1, 4);
            s1 += __shfl_xor(s1, 8);  s1 += __shfl_xor(s1, 16);
            float mu = s1 * (1.f / 32.f);
            float dm = m - mu;
            float s2 = dm * dm;
            s2 += __shfl_xor(s2, 1);  s2 += __shfl_xor(s2, 2);  s2 += __shfl_xor(s2, 4);
            s2 += __shfl_xor(s2, 8);  s2 += __shfl_xor(s2, 16);
            float var = s2 * (1.f / 32.f);
            float g = dm * (1.f / sqrtf(var + 1e-5f)) * gw + gb;
            pe += fmaxf(g, 0.2f * g);              // leaky, residual add
        };
        point(pe0, Av0, A2l0, dkl0);
        point(pe1, Av1, A2l1, dkl1);
    }

    out[n0 * DAT + lane]       = pe0;
    out[(n0 + 1) * DAT + lane] = pe1;
}

// ---------------- launch ----------------
extern "C" void kernel_launch(void* const* d_in, const int* in_sizes, int n_in,
                              void* d_out, int out_size, void* d_ws, size_t ws_size,
                              hipStream_t stream) {
    const float* x     = (const float*)d_in[0];
    const float* y     = (const float*)d_in[1];
    const float* feats = (const float*)d_in[2];
    const float* W1    = (const float*)d_in[3];
    const float* b1    = (const float*)d_in[4];
    const float* W2    = (const float*)d_in[5];
    const float* b2    = (const float*)d_in[6];
    const float* gnw   = (const float*)d_in[7];
    const float* gnb   = (const float*)d_in[8];
    float* out = (float*)d_out;

    char* ws = (char*)d_ws;
    float4*    ypc   = (float4*)  ws;                        // 160,000 B
    int*       oidx  = (int*)    (ws + 160000);              // 1,280,000 B
    float*     odist = (float*)  (ws + 1440000);             // 1,280,000 B
    _Float16*  A     = (_Float16*)(ws + 2720000);            // 7,920,000 B
    int*       starts= (int*)    (ws + 10640000);            // (13824+1)*4
    int*       cursor= (int*)    (ws + 10700000);            // 13824*4
    int*       counts= (int*)    (ws + 10760000);            // (13824+1)*4
    int*       acell = (int*)    (ws + 10820000);            // 10000*4
    int*       aidx  = (int*)    (ws + 10860000);            // 10000*4
    // total ~10.9 MB of ws

    grid_zero   <<<dim3((NCELL + 256) / 256), dim3(256), 0, stream>>>(counts);
    grid_count  <<<dim3((M_ATOMS + 255) / 256), dim3(256), 0, stream>>>(y, counts, acell);
    grid_scan   <<<dim3(1), dim3(1024), 0, stream>>>(counts, starts, cursor);
    grid_scatter<<<dim3((M_ATOMS + 255) / 256), dim3(256), 0, stream>>>(y, acell, cursor, ypc, aidx);
    knn_pre     <<<dim3(KNN_NBLK + PRE_NBLK), dim3(256), 0, stream>>>(
                    x, y, starts, ypc, aidx, oidx, odist, feats, W1, b1, A);
    mlp_fused   <<<dim3(625), dim3(1024), 0, stream>>>(W1, W2, b2, gnw, gnb, A, oidx, odist, out);
}

// Round 15
// 244.061 us; speedup vs baseline: 1.0907x; 1.0907x over previous
//
#include <hip/hip_runtime.h>

#define N_PTS   20000
#define M_ATOMS 10000
#define DAT     64
#define HID     129
#define KNN     16
#define NLAYERS 3

#define A_HSTRIDE  132        // A row stride in HALVES (264 B, 8B-aligned)

#define GRIDL   24
#define NCELL   (GRIDL*GRIDL*GRIDL)   // 13824
#define CELL_H  4.0f
#define INV_H   0.25f
#define GORIG   (-48.0f)

#define KNN_NBLK   (N_PTS / 4)                    // 5000
#define A_GROUPS   (M_ATOMS / 8)                  // 1250 (8 atoms/wave)
#define PRE_NBLK   ((NLAYERS * A_GROUPS + 3) / 4) // 938

typedef _Float16 half2_t __attribute__((ext_vector_type(2)));

__device__ __forceinline__ float readlane_f(float v, int l) {
    return __int_as_float(__builtin_amdgcn_readlane(__float_as_int(v), l));
}
__device__ __forceinline__ int cell_of(float v) {
    int c = (int)floorf((v - GORIG) * INV_H);
    return c < 0 ? 0 : (c > GRIDL - 1 ? GRIDL - 1 : c);
}

// ================= grid build (h=4) =================
__global__ void grid_zero(int* __restrict__ counts) {
    int i = blockIdx.x * 256 + threadIdx.x;
    if (i <= NCELL) counts[i] = 0;
}

__global__ void grid_count(const float* __restrict__ y, int* __restrict__ counts,
                           int* __restrict__ acell) {
    int i = blockIdx.x * 256 + threadIdx.x;
    if (i >= M_ATOMS) return;
    float a = y[3*i], b = y[3*i+1], c = y[3*i+2];
    int cid = (cell_of(c) * GRIDL + cell_of(b)) * GRIDL + cell_of(a);
    acell[i] = cid;
    atomicAdd(&counts[cid], 1);
}

__global__ __launch_bounds__(1024) void grid_scan(const int* __restrict__ counts,
        int* __restrict__ starts, int* __restrict__ cursor) {
    __shared__ int part[1024];
    const int t = threadIdx.x;
    const int base = t * 14;                       // 1024*14 = 14336 >= 13824
    int loc[14]; int sum = 0;
#pragma unroll
    for (int i = 0; i < 14; ++i) {
        int idx = base + i;
        int c = (idx < NCELL) ? counts[idx] : 0;
        loc[i] = sum; sum += c;
    }
    part[t] = sum;
    for (int o = 1; o < 1024; o <<= 1) {
        __syncthreads();
        int v = (t >= o) ? part[t - o] : 0;
        __syncthreads();
        part[t] += v;
    }
    __syncthreads();
    int prev = (t > 0) ? part[t - 1] : 0;
#pragma unroll
    for (int i = 0; i < 14; ++i) {
        int idx = base + i;
        if (idx < NCELL) { int s = prev + loc[i]; starts[idx] = s; cursor[idx] = s; }
    }
    if (t == 1023) starts[NCELL] = part[1023];
}

__global__ void grid_scatter(const float* __restrict__ y, const int* __restrict__ acell,
                             int* __restrict__ cursor, float4* __restrict__ ypc,
                             int* __restrict__ aidx) {
    int i = blockIdx.x * 256 + threadIdx.x;
    if (i >= M_ATOMS) return;
    int cid = acell[i];
    int pos = atomicAdd(&cursor[cid], 1);
    float a = y[3*i], b = y[3*i+1], c = y[3*i+2];
    ypc[pos]  = make_float4(a, b, c, (a*a + b*b) + c*c);   // (y**2).sum(1) order
    aidx[pos] = i;
}

// ================= top-k primitive =================
__device__ __forceinline__ void topk_process(float d2, int ai, int lane,
        float& Ld, int& Li, float& kth, int& kidx, bool& filled) {
    const float INF = __builtin_inff();
    if (!filled) {                                  // bitonic-sort fill (wave-uniform)
        float v = d2; int ix = ai;
#pragma unroll
        for (int k = 2; k <= 64; k <<= 1)
#pragma unroll
            for (int j = k >> 1; j > 0; j >>= 1) {
                float ov = __shfl_xor(v, j);
                int   oi = __shfl_xor(ix, j);
                bool keepmin = (((lane & k) == 0) == ((lane & j) == 0));
                bool oless   = (ov < v) || (ov == v && oi < ix);
                bool take    = (keepmin == oless);
                v  = take ? ov : v;
                ix = take ? oi : ix;
            }
        Ld = (lane < KNN) ? v : INF;
        Li = (lane < KNN) ? ix : 0x7fffffff;
        kth  = readlane_f(v, 15);
        kidx = __builtin_amdgcn_readlane(ix, 15);
        filled = true;
        return;
    }
    bool adm = (d2 < kth) || (d2 == kth && ai < kidx);
    unsigned long long cand = __ballot(adm);
    if (cand) {
        do {
            int src = __builtin_ctzll(cand);
            cand &= cand - 1;
            float v  = readlane_f(d2, src);
            int   mi = __builtin_amdgcn_readlane(ai, src);
            bool pred = (Ld > v) || (Ld == v && Li > mi);   // lexicographic
            unsigned long long bal = __ballot(pred);
            int ins = __builtin_ctzll(bal);
            float pd = __shfl_up(Ld, 1);
            int   pi = __shfl_up(Li, 1);
            bool atins = (lane == ins);
            float tv = atins ? v  : pd;
            int   ti = atins ? mi : pi;
            Ld = pred ? tv : Ld;
            Li = pred ? ti : Li;
        } while (cand);
        kth  = readlane_f(Ld, 15);
        kidx = __builtin_amdgcn_readlane(Li, 15);
    }
}

// ================= fat kernel: knn query (blocks 0..4999) + A precompute =================
__global__ __launch_bounds__(256) void knn_pre(
        const float* __restrict__ x, const float* __restrict__ y,
        const int* __restrict__ starts, const float4* __restrict__ ypc,
        const int* __restrict__ aidx,
        int* __restrict__ oidx, float* __restrict__ odist,
        const float* __restrict__ feats, const float* __restrict__ W1,
        const float* __restrict__ b1, _Float16* __restrict__ A) {
    __shared__ int s_start[4][64];
    __shared__ int s_off[4][64];
    const int lane = threadIdx.x & 63;
    const int wid  = threadIdx.x >> 6;

    if (blockIdx.x >= KNN_NBLK) {
        // ---------- per-atom precompute: A[l][i] = feats[i] @ W1[l][64:128] + b1[l] (fp16) ----------
        int id = (blockIdx.x - KNN_NBLK) * 4 + wid;
        if (id >= NLAYERS * A_GROUPS) return;
        int l = id / A_GROUPS, g = id - l * A_GROUPS;
        int base_atom = g * 8;

        float f[8];
#pragma unroll
        for (int a = 0; a < 8; ++a) f[a] = feats[(base_atom + a) * DAT + lane];
        float a0[8], a1[8], a2[8];
#pragma unroll
        for (int a = 0; a < 8; ++a) { a0[a] = 0.f; a1[a] = 0.f; a2[a] = 0.f; }

        const float* Wl = W1 + (size_t)l * HID * HID;
#pragma unroll 4
        for (int d = 0; d < DAT; ++d) {
            const float* row = Wl + (64 + d) * HID;
            float w0 = row[2 * lane];
            float w1 = row[2 * lane + 1];
            float w2 = row[128];
#pragma unroll
            for (int a = 0; a < 8; ++a) {
                float s = readlane_f(f[a], d);
                a0[a] += s * w0;
                a1[a] += s * w1;
                a2[a] += s * w2;
            }
        }
        const float* b1l = b1 + l * HID;
        float bb0 = b1l[2 * lane], bb1 = b1l[2 * lane + 1], bb2 = b1l[128];
#pragma unroll
        for (int a = 0; a < 8; ++a) {
            _Float16* Ar = A + ((size_t)l * M_ATOMS + base_atom + a) * A_HSTRIDE;
            half2_t hv; hv.x = (_Float16)(a0[a] + bb0); hv.y = (_Float16)(a1[a] + bb1);
            ((half2_t*)Ar)[lane] = hv;
            if (lane == 0) Ar[128] = (_Float16)(a2[a] + bb2);
        }
        return;
    }

    // ---------- kNN query ----------
    const int n = blockIdx.x * 4 + wid;             // < 20000
    const float INF = __builtin_inff();

    const float qx = x[3*n], qy = x[3*n+1], qz = x[3*n+2];
    const float qs = (qx*qx + qy*qy) + qz*qz;       // (x**2).sum(1) order
    const int cx = cell_of(qx), cy = cell_of(qy), cz = cell_of(qz);

    float Ld = INF; int Li = 0x7fffffff;
    float kth = INF; int kidx = 0x7fffffff;
    bool filled = false;

    // ---- rings 0..1: 27 cells, per-cell conservative prune by min-dist to
    // cell box. Center cell first (seeds kth); skip cell iff
    // mindist^2 - 0.25 > kth  (geometric LB <= true d2; ref-algebra d2 >=
    // true - eps, eps << 0.25 -> skipped candidates could never be admitted;
    // kth=INF until filled disables pruning). Exactness preserved.
    {
        int sS = 0, cnt = 0; float mind = INF;
        if (lane < 27) {
            int dxl = lane % 3 - 1, dyv = (lane / 3) % 3 - 1, dzv = lane / 9 - 1;
            int nx = cx + dxl, ny = cy + dyv, nz = cz + dzv;
            if (nx >= 0 && nx < GRIDL && ny >= 0 && ny < GRIDL && nz >= 0 && nz < GRIDL) {
                int cid = (nz * GRIDL + ny) * GRIDL + nx;
                sS  = starts[cid];
                cnt = starts[cid + 1] - sS;
                float lox = GORIG + nx * CELL_H, hix = lox + CELL_H;
                float loy = GORIG + ny * CELL_H, hiy = loy + CELL_H;
                float loz = GORIG + nz * CELL_H, hiz = loz + CELL_H;
                float gx = fmaxf(fmaxf(lox - qx, qx - hix), 0.f);
                float gy = fmaxf(fmaxf(loy - qy, qy - hiy), 0.f);
                float gz = fmaxf(fmaxf(loz - qz, qz - hiz), 0.f);
                mind = gx * gx + gy * gy + gz * gz;  // 0 for center cell
            }
        }
        for (int si = 0; si < 27; ++si) {
            const int s = (si == 0) ? 13 : (si <= 13 ? si - 1 : si);  // center first
            const int cc = __builtin_amdgcn_readlane(cnt, s);
            if (cc == 0) continue;                   // empty / OOB
            const float md = readlane_f(mind, s);
            if (md - 0.25f > kth) continue;          // provably no admissible candidate
            const int ss = __builtin_amdgcn_readlane(sS, s);
            for (int b = 0; b < cc; b += 64) {
                int pos = b + lane; bool val = pos < cc;
                int a = val ? (ss + pos) : ss;
                float4 av = ypc[a];
                int    ai = aidx[a];
                float dot = (qx * av.x + qy * av.y) + qz * av.z;
                float d2  = (qs - 2.f * dot) + av.w;   // same algebra as reference
                if (!val) { d2 = INF; ai = 0x7fffffff; }
                topk_process(d2, ai, lane, Ld, Li, kth, kidx, filled);
            }
        }
    }

    // shells r>=2 (rare): lane-parallel segments + binary search
    int R = 1;
    while (R < GRIDL) {
        float bnd = (float)R * CELL_H - 0.125f;     // margin covers d2 rounding
        if (bnd * bnd > kth) break;                 // wave-uniform
        const int r  = R + 1;
        const int n1 = 2 * r + 1, m = 2 * r - 1;
        const int C1 = 2 * n1, C2 = 2 * m;
        const int S  = C1 + C2 + 2 * m * m;
        for (int base = 0; base < S; base += 64) {
            int sid = base + lane;
            int sS = 0, cnt = 0;
            if (sid < S) {
                int dy, dz, xlo, xhi;
                if (sid < C1) {
                    dz = (sid < n1) ? -r : r;
                    dy = (sid - ((sid < n1) ? 0 : n1)) - r;
                    xlo = cx - r; xhi = cx + r;
                } else if (sid < C1 + C2) {
                    int i = sid - C1;
                    dy = (i < m) ? -r : r;
                    dz = (i - ((i < m) ? 0 : m)) - (r - 1);
                    xlo = cx - r; xhi = cx + r;
                } else {
                    int i = sid - C1 - C2;
                    int pair = i >> 1, side = i & 1;
                    dz = (pair / m) - (r - 1);
                    dy = (pair % m) - (r - 1);
                    int xx = side ? cx + r : cx - r;
                    xlo = xx; xhi = xx;
                }
                int ny = cy + dy, nz = cz + dz;
                if (ny >= 0 && ny < GRIDL && nz >= 0 && nz < GRIDL) {
                    int xl = max(xlo, 0), xh = min(xhi, GRIDL - 1);
                    if (xl <= xh) {
                        int cid0 = (nz * GRIDL + ny) * GRIDL + xl;
                        sS  = starts[cid0];
                        cnt = starts[cid0 + (xh - xl) + 1] - sS;
                    }
                }
            }
            int incl = cnt;
#pragma unroll
            for (int o = 1; o < 64; o <<= 1) {
                int v = __shfl_up(incl, o);
                if (lane >= o) incl += v;
            }
            const int T = __builtin_amdgcn_readlane(incl, 63);
            if (T == 0) continue;
            s_start[wid][lane] = sS;
            s_off[wid][lane]   = incl - cnt;
            for (int b = 0; b < T; b += 64) {
                int pos = b + lane; bool val = pos < T;
                int c = 0;
                c += (s_off[wid][c + 32] <= pos) ? 32 : 0;
                c += (s_off[wid][c + 16] <= pos) ? 16 : 0;
                c += (s_off[wid][c + 8]  <= pos) ? 8  : 0;
                c += (s_off[wid][c + 4]  <= pos) ? 4  : 0;
                c += (s_off[wid][c + 2]  <= pos) ? 2  : 0;
                c += (s_off[wid][c + 1]  <= pos) ? 1  : 0;
                int a = s_start[wid][c] + (pos - s_off[wid][c]);
                a = val ? a : 0;
                float4 av = ypc[a];
                int    ai = aidx[a];
                float dot = (qx * av.x + qy * av.y) + qz * av.z;
                float d2  = (qs - 2.f * dot) + av.w;
                if (!val) { d2 = INF; ai = 0x7fffffff; }
                topk_process(d2, ai, lane, Ld, Li, kth, kidx, filled);
            }
        }
        R = r;
    }

    if (lane < KNN) {
        int ii = Li;
        float ax = y[3*ii], ay = y[3*ii+1], az = y[3*ii+2];
        float ddx = qx - ax, ddy = qy - ay, ddz = qz - az;
        float dist = (ddx*ddx + ddy*ddy) + ddz*ddz;   // ((x-y)**2).sum(-1) order
        oidx [n * KNN + lane] = ii;
        odist[n * KNN + lane] = dist;
    }
}

// ================= fused 3-layer MLP + groupnorm =================
// EXACT round-10 version (141 us measured): 512 threads, plain bounds,
// f32 weights in LDS (64KB), sequential points. Do not touch.
__global__ __launch_bounds__(512) void mlp_fused(
        const float* __restrict__ W1, const float* __restrict__ W2,
        const float* __restrict__ b2, const float* __restrict__ gnw,
        const float* __restrict__ gnb, const _Float16* __restrict__ A,
        const int* __restrict__ oidx, const float* __restrict__ odist,
        float* __restrict__ out) {
    __shared__ float2 w1s[64 * 64];   // [d][lane] = (W1[d][2l], W1[d][2l+1])   32KB
    __shared__ float2 w2s[64 * 64];   // [j][lane] = (W2[2j][l..], W2[2j+1][..]) 32KB
    const int wave = threadIdx.x >> 6, lane = threadIdx.x & 63;
    const int n0 = (blockIdx.x * 8 + wave) * 2;     // 1250*8*2 == 20000

    int ikl0 = 0, ikl1 = 0; float dkl0 = 0.f, dkl1 = 0.f;
    if (lane < KNN) {
        ikl0 = oidx[n0 * KNN + lane];       dkl0 = odist[n0 * KNN + lane];
        ikl1 = oidx[(n0 + 1) * KNN + lane]; dkl1 = odist[(n0 + 1) * KNN + lane];
    }
    float pe0 = 1.f, pe1 = 1.f;

    for (int l = 0; l < NLAYERS; ++l) {
        if (l) __syncthreads();                    // prev layer done reading LDS
        const float* Wl  = W1 + (size_t)l * HID * HID;
        const float* W2l = W2 + (size_t)l * HID * DAT;
        for (int d = wave; d < 64; d += 8) {
            w1s[d * 64 + lane] = make_float2(Wl[d * HID + 2 * lane], Wl[d * HID + 2 * lane + 1]);
            w2s[d * 64 + lane] = make_float2(W2l[(2 * d) * DAT + lane], W2l[(2 * d + 1) * DAT + lane]);
        }
        const float wl0 = Wl[128 * HID + 2 * lane], wl1 = Wl[128 * HID + 2 * lane + 1];
        const float wl2 = Wl[128 * HID + 128];
        const float w1c = Wl[lane * HID + 128];
        const float w2c = W2l[128 * DAT + lane];
        const float b2v = 16.f * b2[l * DAT + lane];
        const float gw  = gnw[l * DAT + lane], gb = gnb[l * DAT + lane];

        // issue gathered-A loads BEFORE the staging barrier (hidden under it)
        const _Float16* Al = A + (size_t)l * M_ATOMS * A_HSTRIDE;
        half2_t Av0[KNN], Av1[KNN];
#pragma unroll
        for (int k = 0; k < KNN; ++k) {
            int i0 = __builtin_amdgcn_readlane(ikl0, k);
            int i1 = __builtin_amdgcn_readlane(ikl1, k);
            Av0[k] = ((const half2_t*)(Al + (size_t)i0 * A_HSTRIDE))[lane];
            Av1[k] = ((const half2_t*)(Al + (size_t)i1 * A_HSTRIDE))[lane];
        }
        float A2l0 = 0.f, A2l1 = 0.f;              // lane k holds channel-128 of neighbor k
        if (lane < KNN) {
            A2l0 = (float)Al[(size_t)ikl0 * A_HSTRIDE + 128];
            A2l1 = (float)Al[(size_t)ikl1 * A_HSTRIDE + 128];
        }
        __syncthreads();                           // weights staged

        // layer 0: pe == 1 -> p-vector identical for all points
        float fpa = 0.f, fpb = 0.f, fpc = 0.f;
        if (l == 0) {
#pragma unroll 8
            for (int d = 0; d < 64; ++d) {
                float2 w = w1s[d * 64 + lane];
                fpa += w.x; fpb += w.y;
            }
            float v = w1c;
            v += __shfl_xor(v, 1);  v += __shfl_xor(v, 2);  v += __shfl_xor(v, 4);
            v += __shfl_xor(v, 8);  v += __shfl_xor(v, 16); v += __shfl_xor(v, 32);
            fpc = v;
        }

        auto point = [&](float& pe, const half2_t* Av, float A2l, float dkl) {
            float p0, p1, p2;
            if (l == 0) { p0 = fpa; p1 = fpb; p2 = fpc; }
            else {
                p0 = 0.f; p1 = 0.f;
#pragma unroll 8
                for (int d = 0; d < 64; ++d) {
                    float s = readlane_f(pe, d);
                    float2 w = w1s[d * 64 + lane];
                    p0 += w.x * s;
                    p1 += w.y * s;
                }
                float v = pe * w1c;                // dot(pe, W1[:,128]) via reduce
                v += __shfl_xor(v, 1);  v += __shfl_xor(v, 2);  v += __shfl_xor(v, 4);
                v += __shfl_xor(v, 8);  v += __shfl_xor(v, 16); v += __shfl_xor(v, 32);
                p2 = v;
            }

            // hsum = sum_k leaky(p + A[idx_k] + dist_k * wl)
            float hs0 = 0.f, hs1 = 0.f, hs2 = 0.f;
#pragma unroll
            for (int k = 0; k < KNN; ++k) {
                float ddk = readlane_f(dkl, k);
                float A2  = readlane_f(A2l, k);
                float A0 = (float)Av[k].x, A1 = (float)Av[k].y;
                float h0 = p0 + A0 + ddk * wl0; h0 = h0 >= 0.f ? h0 : 0.2f * h0; hs0 += h0;
                float h1 = p1 + A1 + ddk * wl1; h1 = h1 >= 0.f ? h1 : 0.2f * h1; hs1 += h1;
                float h2 = p2 + A2 + ddk * wl2; h2 = h2 >= 0.f ? h2 : 0.2f * h2; hs2 += h2;
            }

            // msg = hsum @ W2[l] + K*b2[l]
            float m0 = 0.f, m1 = 0.f;
#pragma unroll 8
            for (int j = 0; j < 64; j += 2) {
                float a0 = readlane_f(hs0, j),     a1 = readlane_f(hs1, j);
                float b0 = readlane_f(hs0, j + 1), b1 = readlane_f(hs1, j + 1);
                float2 wa = w2s[j * 64 + lane];
                float2 wb = w2s[(j + 1) * 64 + lane];
                m0 += wa.x * a0; m0 += wa.y * a1;
                m1 += wb.x * b0; m1 += wb.y * b1;
            }
            float m = (m0 + m1) + hs2 * w2c + b2v;

            // GroupNorm(2 groups of 32 channels) within aligned 32-lane halves
            float s1 = m;
            s1 += __shfl_xor(s1, 1);  s1 += __shfl_xor(s1, 2);  s1 += __shfl_xor(s1, 4);
            s1 += __shfl_xor(s1, 8);  s1 += __shfl_xor(s1, 16);
            float mu = s1 * (1.f / 32.f);
            float dm = m - mu;
            float s2 = dm * dm;
            s2 += __shfl_xor(s2, 1);  s2 += __shfl_xor(s2, 2);  s2 += __shfl_xor(s2, 4);
            s2 += __shfl_xor(s2, 8);  s2 += __shfl_xor(s2, 16);
            float var = s2 * (1.f / 32.f);
            float g = dm * (1.f / sqrtf(var + 1e-5f)) * gw + gb;
            pe += (g >= 0.f) ? g : 0.2f * g;       // leaky, residual add
        };
        point(pe0, Av0, A2l0, dkl0);
        point(pe1, Av1, A2l1, dkl1);
    }

    out[n0 * DAT + lane]       = pe0;
    out[(n0 + 1) * DAT + lane] = pe1;
}

// ---------------- launch ----------------
extern "C" void kernel_launch(void* const* d_in, const int* in_sizes, int n_in,
                              void* d_out, int out_size, void* d_ws, size_t ws_size,
                              hipStream_t stream) {
    const float* x     = (const float*)d_in[0];
    const float* y     = (const float*)d_in[1];
    const float* feats = (const float*)d_in[2];
    const float* W1    = (const float*)d_in[3];
    const float* b1    = (const float*)d_in[4];
    const float* W2    = (const float*)d_in[5];
    const float* b2    = (const float*)d_in[6];
    const float* gnw   = (const float*)d_in[7];
    const float* gnb   = (const float*)d_in[8];
    float* out = (float*)d_out;

    char* ws = (char*)d_ws;
    float4*    ypc   = (float4*)  ws;                        // 160,000 B
    int*       oidx  = (int*)    (ws + 160000);              // 1,280,000 B
    float*     odist = (float*)  (ws + 1440000);             // 1,280,000 B
    _Float16*  A     = (_Float16*)(ws + 2720000);            // 7,920,000 B
    int*       starts= (int*)    (ws + 10640000);            // (13824+1)*4
    int*       cursor= (int*)    (ws + 10700000);            // 13824*4
    int*       counts= (int*)    (ws + 10760000);            // (13824+1)*4
    int*       acell = (int*)    (ws + 10820000);            // 10000*4
    int*       aidx  = (int*)    (ws + 10860000);            // 10000*4
    // total ~10.9 MB of ws

    grid_zero   <<<dim3((NCELL + 256) / 256), dim3(256), 0, stream>>>(counts);
    grid_count  <<<dim3((M_ATOMS + 255) / 256), dim3(256), 0, stream>>>(y, counts, acell);
    grid_scan   <<<dim3(1), dim3(1024), 0, stream>>>(counts, starts, cursor);
    grid_scatter<<<dim3((M_ATOMS + 255) / 256), dim3(256), 0, stream>>>(y, acell, cursor, ypc, aidx);
    knn_pre     <<<dim3(KNN_NBLK + PRE_NBLK), dim3(256), 0, stream>>>(
                    x, y, starts, ypc, aidx, oidx, odist, feats, W1, b1, A);
    mlp_fused   <<<dim3(1250), dim3(512), 0, stream>>>(W1, W2, b2, gnw, gnb, A, oidx, odist, out);
}